// Round 1
// baseline (24091.722 us; speedup 1.0000x reference)
//
#include <hip/hip_runtime.h>
#include <math.h>

#define SLEN 8192
#define DIM  256
#define H2N  256
#define G4   1024
#define NTAG 16
#define NEGV (-10000.0f)

// ws layout (float offsets unless noted)
#define OFF_PRE_F   0
#define OFF_PRE_B   (SLEN*G4)
#define OFF_HS_F    (2*SLEN*G4)
#define OFF_HS_B    (2*SLEN*G4 + SLEN*H2N)
#define OFF_FEATS   (2*SLEN*G4 + 2*SLEN*H2N)
#define OFF_MBOX    (OFF_FEATS + SLEN*NTAG)      // 2 dir x 2 buf x 256
#define WS_NEEDED   ((size_t)(OFF_MBOX + 1024) * 4)

// ---------------- K1: pre = gather(emb, sentence[±]) @ w_ih^T + b ----------------
__global__ __launch_bounds__(256) void gemm_pre(
    const int* __restrict__ sent, const float* __restrict__ emb,
    const float* __restrict__ wf, const float* __restrict__ bf,
    const float* __restrict__ wb, const float* __restrict__ bb,
    float* __restrict__ pre_f, float* __restrict__ pre_b)
{
    const int dir = blockIdx.z;
    const float* w    = dir ? wb : wf;
    const float* bias = dir ? bb : bf;
    float* out        = dir ? pre_b : pre_f;
    const int m0 = blockIdx.x * 64, n0 = blockIdx.y * 64;

    __shared__ float As[16][68];   // [k][m], row stride 272 B (16B-aligned)
    __shared__ float Bs[16][68];   // [k][n]
    __shared__ int   sidx[64];

    const int tid = threadIdx.x;
    const int tx = tid & 15, ty = tid >> 4;

    if (tid < 64) {
        int m = m0 + tid;
        int pos = dir ? (SLEN - 1 - m) : m;
        sidx[tid] = sent[pos];
    }
    __syncthreads();

    float acc[4][4];
#pragma unroll
    for (int i = 0; i < 4; i++)
#pragma unroll
        for (int j = 0; j < 4; j++) acc[i][j] = 0.f;

    const int lr = tid >> 2, lc = (tid & 3) * 4;

    for (int k0 = 0; k0 < DIM; k0 += 16) {
        float4 av = *(const float4*)(emb + (size_t)sidx[lr] * DIM + k0 + lc);
        float4 bv = *(const float4*)(w + (size_t)(n0 + lr) * DIM + k0 + lc);
        As[lc+0][lr] = av.x; As[lc+1][lr] = av.y; As[lc+2][lr] = av.z; As[lc+3][lr] = av.w;
        Bs[lc+0][lr] = bv.x; Bs[lc+1][lr] = bv.y; Bs[lc+2][lr] = bv.z; Bs[lc+3][lr] = bv.w;
        __syncthreads();
#pragma unroll
        for (int k = 0; k < 16; k++) {
            float4 a4 = *(const float4*)&As[k][ty * 4];
            float4 b4 = *(const float4*)&Bs[k][tx * 4];
            float a[4] = {a4.x, a4.y, a4.z, a4.w};
            float b[4] = {b4.x, b4.y, b4.z, b4.w};
#pragma unroll
            for (int i = 0; i < 4; i++)
#pragma unroll
                for (int j = 0; j < 4; j++) acc[i][j] += a[i] * b[j];
        }
        __syncthreads();
    }

    float4 b4 = *(const float4*)(bias + n0 + tx*4);
#pragma unroll
    for (int i = 0; i < 4; i++) {
        float4 v;
        v.x = acc[i][0] + b4.x; v.y = acc[i][1] + b4.y;
        v.z = acc[i][2] + b4.z; v.w = acc[i][3] + b4.w;
        *(float4*)(out + (size_t)(m0 + ty*4 + i) * G4 + n0 + tx*4) = v;
    }
}

__device__ __forceinline__ float fast_sigmoid(float x) {
    return 1.f / (1.f + __expf(-x));
}
__device__ __forceinline__ float fast_tanh(float x) {
    float xc = fminf(fmaxf(x, -15.f), 15.f);
    float e = __expf(2.f * xc);
    return (e - 1.f) / (e + 1.f);
}

// ---------------- K2: fused bi-dir LSTM, 32 workers on ONE XCD ----------------
// R8 analysis: per step = C(~240cy VALU) + L(~5200cy mailbox exchange). Two
// structural fixes:
//  (a) XCD co-location: workers = blocks with blockIdx%8==0 in a 256-block
//      grid. Under MI300-series round-robin dispatch all 32 workers share one
//      XCD, so mailbox lines stay in ONE L2 and the agent-scope store->poll
//      round trip is L2-latency, not LLC-latency. Heuristic only: if the
//      mapping differs, agent scope is still correct via LLC (perf fallback).
//  (b) Direction fusion + software pipelining: each worker owns 8 cells of
//      BOTH directions. Loop = {poll d0(t); compute d0(t+1); poll d1(t);
//      compute d1(t+1)} so each chain's exchange latency hides under the
//      other chain's compute: period = L + C per step-PAIR, not 2*(L+C).
// Protocol unchanged per dir (2-buffer ping-pong, 1-bit tag in mantissa LSB):
// a producer reaching t+1 must have observed all h_t (incl. any stalled
// consumer's own h_t), so max skew is 1 step; buffer parity separates t/t+1,
// tag bit separates t/t+2. Poison 0xAA (bit0=0) and prior-run leftovers
// (tag 0 at t=8190/8191) both mismatch etag=1 at t=0/1 -> no false positive.
// Single wave per block: LDS ops are program-ordered within a wave, so no
// barrier is needed inside the loop.
__global__ __launch_bounds__(64) void lstm_kernel(
    const float* __restrict__ pre_f, const float* __restrict__ pre_b,
    const float* __restrict__ whh_f, const float* __restrict__ whh_b,
    const float* __restrict__ h0_f, const float* __restrict__ c0_f,
    const float* __restrict__ h0_b, const float* __restrict__ c0_b,
    float* __restrict__ hs_f, float* __restrict__ hs_b,
    unsigned* __restrict__ mbox)
{
    if (blockIdx.x & 7) return;          // XCD co-location: keep b%8==0 only
    const int cb = blockIdx.x >> 3;      // worker id 0..31
    const int cell0 = cb * 8;

    const int l = threadIdx.x;           // 0..63
    const int r = l >> 1;                // local row 0..31 (gate-major)
    const int half = l & 1;              // k-half: [half*128, half*128+128)
    const int g = r >> 3, cl = r & 7;
    const int grow = g * 256 + cell0 + cl;   // global gate row (0..1023)
    const int ai = l & 7;                // activation cell index (lanes 0..7)

    __shared__ __align__(16) float4 w0_pack[32 * 64];   // 32 KB, [j][lane]
    __shared__ __align__(16) float4 w1_pack[32 * 64];   // 32 KB
    __shared__ __align__(16) float  h_lds0[256];
    __shared__ __align__(16) float  h_lds1[256];

    // stage W (both dirs) into packed LDS
    {
        const float4* s0 = (const float4*)(whh_f + (size_t)grow * H2N + half * 128);
        const float4* s1 = (const float4*)(whh_b + (size_t)grow * H2N + half * 128);
#pragma unroll
        for (int j = 0; j < 32; j++) {
            w0_pack[j * 64 + l] = s0[j];
            w1_pack[j * 64 + l] = s1[j];
        }
    }
    ((float4*)h_lds0)[l] = ((const float4*)h0_f)[l];
    ((float4*)h_lds1)[l] = ((const float4*)h0_b)[l];
    float c0r = (l < 8) ? c0_f[cell0 + l] : 0.f;
    float c1r = (l < 8) ? c0_b[cell0 + l] : 0.f;
    __syncthreads();

    const float* preb0 = pre_f + grow;
    const float* preb1 = pre_b + grow;
    unsigned* mbd0 = mbox;
    unsigned* mbd1 = mbox + 512;
    unsigned* hsf_u = (unsigned*)hs_f;
    unsigned* hsb_u = (unsigned*)hs_b;

    // one LSTM step for one direction: gates from (W in LDS, h in LDS, pre),
    // activations on lanes 0..7, publish tagged h to mailbox + history.
#define LSTM_STEP(T, WPACK, HLDS, PRE, CREG, MB, HIST)                         \
    {                                                                          \
        const unsigned etag_ = ((((unsigned)(T)) >> 1) & 1u) ^ 1u;             \
        unsigned* mb_ = (MB) + ((T) & 1) * 256;                                \
        float a0 = (PRE), a1 = 0.f, a2 = 0.f, a3 = 0.f;                        \
        const float4* hr_ = (const float4*)((HLDS) + half * 128);              \
_Pragma("unroll")                                                              \
        for (int j = 0; j < 32; j++) {                                         \
            float4 wv = (WPACK)[j * 64 + l];                                   \
            float4 hv = hr_[j];                                                \
            a0 += wv.x * hv.x; a1 += wv.y * hv.y;                              \
            a2 += wv.z * hv.z; a3 += wv.w * hv.w;                              \
        }                                                                      \
        float sum = (a0 + a1) + (a2 + a3);                                     \
        sum += __shfl_xor(sum, 1, 64);                                         \
        float s_i = __shfl(sum,      2 * ai, 64);                              \
        float s_f = __shfl(sum, 16 + 2 * ai, 64);                              \
        float s_g = __shfl(sum, 32 + 2 * ai, 64);                              \
        float s_o = __shfl(sum, 48 + 2 * ai, 64);                              \
        if (l < 8) {                                                           \
            float i_ = fast_sigmoid(s_i);                                      \
            float f_ = fast_sigmoid(s_f);                                      \
            float g_ = fast_tanh(s_g);                                         \
            float o_ = fast_sigmoid(s_o);                                      \
            (CREG) = f_ * (CREG) + i_ * g_;                                    \
            float h = o_ * fast_tanh(CREG);                                    \
            unsigned hm = (__float_as_uint(h) & ~1u) | etag_;                  \
            __hip_atomic_store(mb_ + cell0 + l, hm,                            \
                               __ATOMIC_RELAXED, __HIP_MEMORY_SCOPE_AGENT);    \
            __builtin_nontemporal_store(hm,                                    \
                (HIST) + (size_t)(T) * H2N + cell0 + l);                       \
        }                                                                      \
    }

    // poll one direction's mailbox for step T, scatter into h LDS
#define POLL_DIR(MB, T, HLDS)                                                  \
    {                                                                          \
        const unsigned etag_ = ((((unsigned)(T)) >> 1) & 1u) ^ 1u;             \
        const unsigned* ms_ = (MB) + ((T) & 1) * 256 + 4 * l;                  \
        unsigned v0, v1, v2, v3; int spin_ = 0;                                \
        do {                                                                   \
            v0 = __hip_atomic_load(ms_ + 0, __ATOMIC_RELAXED, __HIP_MEMORY_SCOPE_AGENT); \
            v1 = __hip_atomic_load(ms_ + 1, __ATOMIC_RELAXED, __HIP_MEMORY_SCOPE_AGENT); \
            v2 = __hip_atomic_load(ms_ + 2, __ATOMIC_RELAXED, __HIP_MEMORY_SCOPE_AGENT); \
            v3 = __hip_atomic_load(ms_ + 3, __ATOMIC_RELAXED, __HIP_MEMORY_SCOPE_AGENT); \
        } while ((((v0 ^ etag_) | (v1 ^ etag_) | (v2 ^ etag_) | (v3 ^ etag_)) & 1u) \
                 && ++spin_ < 2000000);                                        \
        float4 hv_;                                                            \
        hv_.x = __uint_as_float(v0); hv_.y = __uint_as_float(v1);              \
        hv_.z = __uint_as_float(v2); hv_.w = __uint_as_float(v3);              \
        *(float4*)((HLDS) + 4 * l) = hv_;                                      \
    }

    // prologue: h_0 for both dirs from initial state
    {
        float p0 = (half == 0) ? preb0[0] : 0.f;
        float p1 = (half == 0) ? preb1[0] : 0.f;
        LSTM_STEP(0, w0_pack, h_lds0, p0, c0r, mbd0, hsf_u);
        LSTM_STEP(0, w1_pack, h_lds1, p1, c1r, mbd1, hsb_u);
    }

    // pipelined main loop: each poll sits immediately before ITS dependent
    // compute, so dir0's exchange hides under dir1's compute and vice versa.
    for (int t = 0; t < SLEN - 1; t++) {
        // issue pre(t+1) loads first: they resolve under the poll spin
        float pn0 = (half == 0) ? preb0[(size_t)(t + 1) * G4] : 0.f;
        float pn1 = (half == 0) ? preb1[(size_t)(t + 1) * G4] : 0.f;

        POLL_DIR(mbd0, t, h_lds0);
        LSTM_STEP(t + 1, w0_pack, h_lds0, pn0, c0r, mbd0, hsf_u);

        POLL_DIR(mbd1, t, h_lds1);
        LSTM_STEP(t + 1, w1_pack, h_lds1, pn1, c1r, mbd1, hsb_u);
    }
#undef LSTM_STEP
#undef POLL_DIR
}

// ---------------- K3: feats = concat(hs_f[s], hs_b[S-1-s]) @ w_out^T + b_out ----------------
__global__ __launch_bounds__(256) void feats_kernel(
    const float* __restrict__ hs_f, const float* __restrict__ hs_b,
    const float* __restrict__ w_out, const float* __restrict__ b_out,
    float* __restrict__ feats)
{
    const int rs0 = blockIdx.x * 16;
    const int tid = threadIdx.x;
    const int r = tid >> 4, cc = tid & 15;

    __shared__ float Hs[16][516];   // row stride 2064 B (16B-aligned)
    for (int i = tid; i < 16 * 256; i += 256) {
        int rr = i >> 8, k = i & 255;
        Hs[rr][k]       = hs_f[(size_t)(rs0 + rr) * H2N + k];
        Hs[rr][256 + k] = hs_b[(size_t)(SLEN - 1 - (rs0 + rr)) * H2N + k];
    }
    __syncthreads();

    float acc = 0.f;
    const float* wr = w_out + (size_t)cc * 512;
    const float* hrow = Hs[r];
#pragma unroll 4
    for (int kq = 0; kq < 128; kq++) {
        float4 hv = *(const float4*)(hrow + 4 * kq);
        float4 wv = *(const float4*)(wr + 4 * kq);
        acc += hv.x * wv.x; acc += hv.y * wv.y;
        acc += hv.z * wv.z; acc += hv.w * wv.w;
    }
    feats[(size_t)(rs0 + r) * NTAG + cc] = acc + b_out[cc];
}

// ---------------- K4: Viterbi scan + backtrack (single wave, LDS back-ptrs) ----------------
__global__ __launch_bounds__(64) void viterbi_kernel(
    const float* __restrict__ feats, const float* __restrict__ trans,
    float* __restrict__ out)
{
    __shared__ unsigned char back_s[SLEN * 8];   // 65536 B, [t][tag/2] nibbles

    const int lane = threadIdx.x;
    const int nx = lane >> 2, pc = lane & 3;   // next tag, prev-chunk

    float tr[4];
#pragma unroll
    for (int j = 0; j < 4; j++) tr[j] = trans[nx * NTAG + pc * 4 + j];

    // score of tag g lives (replicated) in lanes 4g..4g+3
    float sc = (nx == 0) ? 0.f : NEGV;
    float fe = feats[nx];   // prefetch t=0

    for (int t = 0; t < SLEN; t++) {
        float fe_next = (t < SLEN - 1) ? feats[(size_t)(t + 1) * NTAG + nx] : 0.f;

        float bv; int bi;
#pragma unroll
        for (int j = 0; j < 4; j++) {
            float s = __shfl(sc, 4 * (pc * 4 + j), 64);
            float cand = s + tr[j];
            if (j == 0) { bv = cand; bi = pc * 4; }
            else if (cand > bv) { bv = cand; bi = pc * 4 + j; }
        }
        // combine across the 4 prev-chunks; first-max semantics (tie -> smaller idx)
#pragma unroll
        for (int off = 1; off < 4; off <<= 1) {
            float ov = __shfl_xor(bv, off, 64);
            int   oi = __shfl_xor(bi, off, 64);
            if (ov > bv || (ov == bv && oi < bi)) { bv = ov; bi = oi; }
        }
        // nibble-pack: lane (nx even, pc==0) stores [bi(nx) | bi(nx+1)<<4]
        int bi_part = __shfl(bi, (nx | 1) * 4, 64);
        if (pc == 0 && (nx & 1) == 0)
            back_s[t * 8 + (nx >> 1)] = (unsigned char)((bi & 15) | (bi_part << 4));
        sc = bv + fe;
        fe = fe_next;
    }

    // final = last + trans[END=1]; first-argmax
    float bestv = 0.f; int besti = 0;
#pragma unroll
    for (int j = 0; j < NTAG; j++) {
        float sj = __shfl(sc, 4 * j, 64);
        float fj = sj + trans[1 * NTAG + j];
        if (j == 0) { bestv = fj; besti = 0; }
        else if (fj > bestv) { bestv = fj; besti = j; }
    }
    __syncthreads();

    if (lane == 0) {
        out[0] = bestv;
        int cur = besti;
        for (int t = SLEN - 1; t >= 1; t--) {
            out[1 + t] = (float)cur;
            unsigned char byte = back_s[t * 8 + (cur >> 1)];
            cur = (cur & 1) ? (byte >> 4) : (byte & 15);
        }
        out[1] = (float)cur;
    }
}

extern "C" void kernel_launch(void* const* d_in, const int* in_sizes, int n_in,
                              void* d_out, int out_size, void* d_ws, size_t ws_size,
                              hipStream_t stream) {
    const int*   sent   = (const int*)d_in[0];
    const float* emb    = (const float*)d_in[1];
    const float* w_ih_f = (const float*)d_in[2];
    const float* w_hh_f = (const float*)d_in[3];
    const float* b_f    = (const float*)d_in[4];
    const float* w_ih_b = (const float*)d_in[5];
    const float* w_hh_b = (const float*)d_in[6];
    const float* b_b    = (const float*)d_in[7];
    const float* h0_f   = (const float*)d_in[8];
    const float* c0_f   = (const float*)d_in[9];
    const float* h0_b   = (const float*)d_in[10];
    const float* c0_b   = (const float*)d_in[11];
    const float* w_out  = (const float*)d_in[12];
    const float* b_out  = (const float*)d_in[13];
    const float* trans  = (const float*)d_in[14];
    float* out = (float*)d_out;

    if (ws_size < WS_NEEDED) return;  // visible failure, no OOB writes

    float* ws = (float*)d_ws;
    float* pre_f = ws + OFF_PRE_F;
    float* pre_b = ws + OFF_PRE_B;
    float* hs_f  = ws + OFF_HS_F;
    float* hs_b  = ws + OFF_HS_B;
    float* feats = ws + OFF_FEATS;
    unsigned* mbox = (unsigned*)(ws + OFF_MBOX);

    gemm_pre<<<dim3(128, 16, 2), 256, 0, stream>>>(sent, emb, w_ih_f, b_f, w_ih_b, b_b, pre_f, pre_b);
    lstm_kernel<<<256, 64, 0, stream>>>(pre_f, pre_b, w_hh_f, w_hh_b,
                                        h0_f, c0_f, h0_b, c0_b, hs_f, hs_b, mbox);
    feats_kernel<<<512, 256, 0, stream>>>(hs_f, hs_b, w_out, b_out, feats);
    viterbi_kernel<<<1, 64, 0, stream>>>(feats, trans, out);
}